// Round 5
// baseline (197.349 us; speedup 1.0000x reference)
//
#include <hip/hip_runtime.h>
#include <math.h>

#define BB 256
#define DD 5120
#define NN 16
#define RR 160
#define CT 192          // 160 (t) + 16 (Bm) + 16 (Cm)
#define NSPLIT 64
#define KSPL 80         // K per split: 5120/64
#define TMP_ELEMS (BB * CT)          // 49152
#define NEGA_ELEMS (DD * NN)         // 81920

// ---------------- K1: partials[s][b][c] = x[b, ks:ks+80] @ Wcat[ks:ks+80, c]
// grid: (3 c-tiles, 4 b-tiles, 64 k-splits) = 768 blocks, block 256, micro 4x4
__global__ __launch_bounds__(256) void k1_gemm(const float* __restrict__ x,
                                               const float* __restrict__ Wxdt,
                                               const float* __restrict__ Wbc,
                                               float* __restrict__ part) {
    __shared__ float xs[16][68];   // [k][b] transposed
    __shared__ float ws[16][64];   // [k][c]
    const int tid = threadIdx.x;
    const int tx = tid & 15, ty = tid >> 4;
    const int c0 = blockIdx.x * 64;
    const int b0 = blockIdx.y * 64;
    const int k0 = blockIdx.z * KSPL;
    float acc[4][4] = {};

    for (int kc = 0; kc < KSPL; kc += 16) {
        {
            const int row = tid >> 2;        // 0..63
            const int j4  = (tid & 3) * 4;   // 0,4,8,12
            const float4 v = *(const float4*)&x[(size_t)(b0 + row) * DD + k0 + kc + j4];
            xs[j4 + 0][row] = v.x;
            xs[j4 + 1][row] = v.y;
            xs[j4 + 2][row] = v.z;
            xs[j4 + 3][row] = v.w;
        }
        {
            const int r  = tid >> 4;         // 0..15
            const int c4 = (tid & 15) * 4;
            const int kg = k0 + kc + r;
            const int cg = c0 + c4;
            float4 v;
            if (cg < RR) v = *(const float4*)&Wxdt[(size_t)kg * RR + cg];
            else         v = *(const float4*)&Wbc[(size_t)kg * 32 + (cg - RR)];
            *(float4*)&ws[r][c4] = v;
        }
        __syncthreads();
        #pragma unroll
        for (int k = 0; k < 16; ++k) {
            const float4 a4 = *(const float4*)&xs[k][ty * 4];
            const float4 w4 = *(const float4*)&ws[k][tx * 4];
            const float av[4] = {a4.x, a4.y, a4.z, a4.w};
            const float wv[4] = {w4.x, w4.y, w4.z, w4.w};
            #pragma unroll
            for (int u = 0; u < 4; ++u)
                #pragma unroll
                for (int v = 0; v < 4; ++v)
                    acc[u][v] = fmaf(av[u], wv[v], acc[u][v]);
        }
        __syncthreads();
    }

    float* p = part + (size_t)blockIdx.z * TMP_ELEMS;
    #pragma unroll
    for (int u = 0; u < 4; ++u) {
        const int b = b0 + ty * 4 + u;
        *(float4*)&p[b * CT + c0 + tx * 4] =
            make_float4(acc[u][0], acc[u][1], acc[u][2], acc[u][3]);
    }
}

// ---------------- K_RED: tmp = sum_s partials; negA = -exp(A_log) -----------
// grid: 512 blocks x 256 = 131072 threads = 49152 + 81920
__global__ __launch_bounds__(256) void k_red(const float* __restrict__ part,
                                             const float* __restrict__ Alog,
                                             float* __restrict__ tmp,
                                             float* __restrict__ negA) {
    const int idx = blockIdx.x * 256 + threadIdx.x;
    if (idx < TMP_ELEMS) {
        float s = 0.f;
        #pragma unroll
        for (int z = 0; z < NSPLIT; ++z) s += part[(size_t)z * TMP_ELEMS + idx];
        tmp[idx] = s;
    } else {
        const int j = idx - TMP_ELEMS;
        negA[j] = -__expf(Alog[j]);
    }
}

// ---------------- K2: dt[b,d] = softplus(t @ W_dt + b_dt) -------------------
// grid: (80 d-tiles of 64, 8 b-tiles of 32), block 256, micro 2b x 4d
__global__ __launch_bounds__(256) void k2_dt(const float* __restrict__ tmp,
                                             const float* __restrict__ Wdt,
                                             const float* __restrict__ bdt,
                                             float* __restrict__ dt) {
    __shared__ float ts[32][34];
    __shared__ float ws[32][64];
    const int tid = threadIdx.x;
    const int tx = tid & 15, ty = tid >> 4;
    const int d0 = blockIdx.x * 64;
    const int b0 = blockIdx.y * 32;
    float acc[2][4] = {};

    for (int kc = 0; kc < RR; kc += 32) {
        {
            const int row = tid >> 3;         // 0..31 (b)
            const int j4  = (tid & 7) * 4;    // 0..28 (k)
            const float4 v = *(const float4*)&tmp[(size_t)(b0 + row) * CT + kc + j4];
            ts[j4 + 0][row] = v.x;
            ts[j4 + 1][row] = v.y;
            ts[j4 + 2][row] = v.z;
            ts[j4 + 3][row] = v.w;
        }
        {
            const int c4 = (tid & 15) * 4;
            const int r0 = tid >> 4;
            #pragma unroll
            for (int rep = 0; rep < 2; ++rep) {
                const int r = r0 + rep * 16;
                *(float4*)&ws[r][c4] = *(const float4*)&Wdt[(size_t)(kc + r) * DD + d0 + c4];
            }
        }
        __syncthreads();
        #pragma unroll
        for (int k = 0; k < 32; ++k) {
            const float a0 = ts[k][ty * 2 + 0];
            const float a1 = ts[k][ty * 2 + 1];
            const float4 w4 = *(const float4*)&ws[k][tx * 4];
            const float wv[4] = {w4.x, w4.y, w4.z, w4.w};
            #pragma unroll
            for (int v = 0; v < 4; ++v) {
                acc[0][v] = fmaf(a0, wv[v], acc[0][v]);
                acc[1][v] = fmaf(a1, wv[v], acc[1][v]);
            }
        }
        __syncthreads();
    }

    const float4 bv = *(const float4*)&bdt[d0 + tx * 4];
    const float bb[4] = {bv.x, bv.y, bv.z, bv.w};
    #pragma unroll
    for (int u = 0; u < 2; ++u) {
        const int b = b0 + ty * 2 + u;
        float o[4];
        #pragma unroll
        for (int v = 0; v < 4; ++v) {
            const float z = acc[u][v] + bb[v];
            o[v] = fmaxf(z, 0.f) + log1pf(__expf(-fabsf(z)));
        }
        *(float4*)&dt[(size_t)b * DD + d0 + tx * 4] = make_float4(o[0], o[1], o[2], o[3]);
    }
}

// ---------------- K3: pure streaming SSM epilogue ----------------------------
// y[b,d] = sum_n (exp(negA[d,n]*dt)*h0[b,d,n] + dt*x*Bm[b,n]) * Cm[b,n] + x
// grid: (10 d-chunks of 512, 256 b), block 256; thread owns 2 consecutive d.
__global__ __launch_bounds__(256) void k3_ssm(const float* __restrict__ x,
                                              const float* __restrict__ h0,
                                              const float* __restrict__ dt,
                                              const float* __restrict__ tmp,
                                              const float* __restrict__ negA,
                                              float* __restrict__ out) {
    __shared__ float bcS[32];   // Bm [0..15], Cm [16..31] for this b
    const int tid = threadIdx.x;
    const int b   = blockIdx.y;
    const int d2  = blockIdx.x * 512 + tid * 2;
    const size_t base = (size_t)b * DD + d2;

    if (tid < 32) bcS[tid] = tmp[(size_t)b * CT + RR + tid];
    __syncthreads();

    // issue all global loads up front (16 float4 + 2 float2)
    const float2 xe  = *(const float2*)&x[base];
    const float2 dtv = *(const float2*)&dt[base];
    const float* hp = &h0[base * NN];
    float4 ha[4], hb[4];
    #pragma unroll
    for (int i = 0; i < 4; ++i) ha[i] = *(const float4*)&hp[i * 4];
    #pragma unroll
    for (int i = 0; i < 4; ++i) hb[i] = *(const float4*)&hp[NN + i * 4];
    const float* ap = &negA[(size_t)d2 * NN];
    float4 na0[4], na1[4];
    #pragma unroll
    for (int i = 0; i < 4; ++i) na0[i] = *(const float4*)&ap[i * 4];
    #pragma unroll
    for (int i = 0; i < 4; ++i) na1[i] = *(const float4*)&ap[NN + i * 4];

    const float dt0 = dtv.x, dt1 = dtv.y;
    const float dtx0 = dt0 * xe.x;
    const float dtx1 = dt1 * xe.y;

    float bm[NN], cm[NN];
    #pragma unroll
    for (int n = 0; n < NN; ++n) { bm[n] = bcS[n]; cm[n] = bcS[16 + n]; }

    float y0a = xe.x, y0b = 0.f, y1a = xe.y, y1b = 0.f;
    #pragma unroll
    for (int q4 = 0; q4 < 4; ++q4) {
        const float av0[4] = {na0[q4].x, na0[q4].y, na0[q4].z, na0[q4].w};
        const float av1[4] = {na1[q4].x, na1[q4].y, na1[q4].z, na1[q4].w};
        const float hv0[4] = {ha[q4].x, ha[q4].y, ha[q4].z, ha[q4].w};
        const float hv1[4] = {hb[q4].x, hb[q4].y, hb[q4].z, hb[q4].w};
        #pragma unroll
        for (int q = 0; q < 4; ++q) {
            const int n = q4 * 4 + q;
            const float dA0 = __expf(av0[q] * dt0);
            const float h00 = fmaf(dA0, hv0[q], dtx0 * bm[n]);
            const float dA1 = __expf(av1[q] * dt1);
            const float h11 = fmaf(dA1, hv1[q], dtx1 * bm[n]);
            if (n & 1) { y0b = fmaf(h00, cm[n], y0b); y1b = fmaf(h11, cm[n], y1b); }
            else       { y0a = fmaf(h00, cm[n], y0a); y1a = fmaf(h11, cm[n], y1a); }
        }
    }
    *(float2*)&out[base] = make_float2(y0a + y0b, y1a + y1b);
}

extern "C" void kernel_launch(void* const* d_in, const int* in_sizes, int n_in,
                              void* d_out, int out_size, void* d_ws, size_t ws_size,
                              hipStream_t stream) {
    const float* x    = (const float*)d_in[0];
    const float* h0   = (const float*)d_in[1];
    const float* Wxdt = (const float*)d_in[2];
    const float* Wdt  = (const float*)d_in[3];
    const float* bdt  = (const float*)d_in[4];
    const float* Wbc  = (const float*)d_in[5];
    const float* Alog = (const float*)d_in[6];
    float* out = (float*)d_out;

    // ws layout (floats): partials[64*49152] | tmp[49152] | negA[81920] | dt[1310720]
    float* part  = (float*)d_ws;
    float* tmp   = part + (size_t)NSPLIT * TMP_ELEMS;
    float* negA  = tmp + TMP_ELEMS;
    float* dtbuf = negA + NEGA_ELEMS;

    k1_gemm<<<dim3(3, 4, NSPLIT), 256, 0, stream>>>(x, Wxdt, Wbc, part);
    k_red<<<dim3((TMP_ELEMS + NEGA_ELEMS) / 256), 256, 0, stream>>>(part, Alog, tmp, negA);
    k2_dt<<<dim3(DD / 64, BB / 32), 256, 0, stream>>>(tmp, Wdt, bdt, dtbuf);
    k3_ssm<<<dim3(10, BB), 256, 0, stream>>>(x, h0, dtbuf, tmp, negA, out);
}

// Round 6
// 188.215 us; speedup vs baseline: 1.0485x; 1.0485x over previous
//
#include <hip/hip_runtime.h>
#include <math.h>

#define BB 256
#define DD 5120
#define NN 16
#define RR 160
#define CT 192          // 160 (t) + 16 (Bm) + 16 (Cm)
#define NSPLIT 64
#define KSPL 80         // K per split: 5120/64
#define TMP_ELEMS (BB * CT)          // 49152

// ---------------- K1: partials[s][b][c] = x[b, ks:ks+80] @ Wcat[ks:ks+80, c]
// grid: (3 c-tiles, 4 b-tiles, 64 k-splits) = 768 blocks, block 256, micro 4x4
__global__ __launch_bounds__(256) void k1_gemm(const float* __restrict__ x,
                                               const float* __restrict__ Wxdt,
                                               const float* __restrict__ Wbc,
                                               float* __restrict__ part) {
    __shared__ float xs[16][68];   // [k][b] transposed
    __shared__ float ws[16][64];   // [k][c]
    const int tid = threadIdx.x;
    const int tx = tid & 15, ty = tid >> 4;
    const int c0 = blockIdx.x * 64;
    const int b0 = blockIdx.y * 64;
    const int k0 = blockIdx.z * KSPL;
    float acc[4][4] = {};

    for (int kc = 0; kc < KSPL; kc += 16) {
        {
            const int row = tid >> 2;        // 0..63
            const int j4  = (tid & 3) * 4;   // 0,4,8,12
            const float4 v = *(const float4*)&x[(size_t)(b0 + row) * DD + k0 + kc + j4];
            xs[j4 + 0][row] = v.x;
            xs[j4 + 1][row] = v.y;
            xs[j4 + 2][row] = v.z;
            xs[j4 + 3][row] = v.w;
        }
        {
            const int r  = tid >> 4;         // 0..15
            const int c4 = (tid & 15) * 4;
            const int kg = k0 + kc + r;
            const int cg = c0 + c4;
            float4 v;
            if (cg < RR) v = *(const float4*)&Wxdt[(size_t)kg * RR + cg];
            else         v = *(const float4*)&Wbc[(size_t)kg * 32 + (cg - RR)];
            *(float4*)&ws[r][c4] = v;
        }
        __syncthreads();
        #pragma unroll
        for (int k = 0; k < 16; ++k) {
            const float4 a4 = *(const float4*)&xs[k][ty * 4];
            const float4 w4 = *(const float4*)&ws[k][tx * 4];
            const float av[4] = {a4.x, a4.y, a4.z, a4.w};
            const float wv[4] = {w4.x, w4.y, w4.z, w4.w};
            #pragma unroll
            for (int u = 0; u < 4; ++u)
                #pragma unroll
                for (int v = 0; v < 4; ++v)
                    acc[u][v] = fmaf(av[u], wv[v], acc[u][v]);
        }
        __syncthreads();
    }

    float* p = part + (size_t)blockIdx.z * TMP_ELEMS;
    #pragma unroll
    for (int u = 0; u < 4; ++u) {
        const int b = b0 + ty * 4 + u;
        *(float4*)&p[b * CT + c0 + tx * 4] =
            make_float4(acc[u][0], acc[u][1], acc[u][2], acc[u][3]);
    }
}

// ---------------- K_RED: tmp = sum_s partials --------------------------------
// grid: 192 blocks x 256
__global__ __launch_bounds__(256) void k_red(const float* __restrict__ part,
                                             float* __restrict__ tmp) {
    const int idx = blockIdx.x * 256 + threadIdx.x;
    float s = 0.f;
    #pragma unroll
    for (int z = 0; z < NSPLIT; ++z) s += part[(size_t)z * TMP_ELEMS + idx];
    tmp[idx] = s;
}

// ---------------- K2: dt[b,d] = softplus(t @ W_dt + b_dt) -------------------
// grid: (80 d-tiles of 64, 8 b-tiles of 32), block 256, micro 2b x 4d
__global__ __launch_bounds__(256) void k2_dt(const float* __restrict__ tmp,
                                             const float* __restrict__ Wdt,
                                             const float* __restrict__ bdt,
                                             float* __restrict__ dt) {
    __shared__ float ts[32][34];
    __shared__ float ws[32][64];
    const int tid = threadIdx.x;
    const int tx = tid & 15, ty = tid >> 4;
    const int d0 = blockIdx.x * 64;
    const int b0 = blockIdx.y * 32;
    float acc[2][4] = {};

    for (int kc = 0; kc < RR; kc += 32) {
        {
            const int row = tid >> 3;         // 0..31 (b)
            const int j4  = (tid & 7) * 4;    // 0..28 (k)
            const float4 v = *(const float4*)&tmp[(size_t)(b0 + row) * CT + kc + j4];
            ts[j4 + 0][row] = v.x;
            ts[j4 + 1][row] = v.y;
            ts[j4 + 2][row] = v.z;
            ts[j4 + 3][row] = v.w;
        }
        {
            const int c4 = (tid & 15) * 4;
            const int r0 = tid >> 4;
            #pragma unroll
            for (int rep = 0; rep < 2; ++rep) {
                const int r = r0 + rep * 16;
                *(float4*)&ws[r][c4] = *(const float4*)&Wdt[(size_t)(kc + r) * DD + d0 + c4];
            }
        }
        __syncthreads();
        #pragma unroll
        for (int k = 0; k < 32; ++k) {
            const float a0 = ts[k][ty * 2 + 0];
            const float a1 = ts[k][ty * 2 + 1];
            const float4 w4 = *(const float4*)&ws[k][tx * 4];
            const float wv[4] = {w4.x, w4.y, w4.z, w4.w};
            #pragma unroll
            for (int v = 0; v < 4; ++v) {
                acc[0][v] = fmaf(a0, wv[v], acc[0][v]);
                acc[1][v] = fmaf(a1, wv[v], acc[1][v]);
            }
        }
        __syncthreads();
    }

    const float4 bv = *(const float4*)&bdt[d0 + tx * 4];
    const float bb[4] = {bv.x, bv.y, bv.z, bv.w};
    #pragma unroll
    for (int u = 0; u < 2; ++u) {
        const int b = b0 + ty * 2 + u;
        float o[4];
        #pragma unroll
        for (int v = 0; v < 4; ++v) {
            const float z = acc[u][v] + bb[v];
            o[v] = fmaxf(z, 0.f) + log1pf(__expf(-fabsf(z)));
        }
        *(float4*)&dt[(size_t)b * DD + d0 + tx * 4] = make_float4(o[0], o[1], o[2], o[3]);
    }
}

// ---------------- K3: quad-cooperative streaming SSM epilogue ----------------
// lane-quad owns one d; the 4 lanes split the 16 n's (4 each).
// Every h0/Alog wave-load is 1 KB contiguous; dt/x/Bm/Cm are quad-broadcast.
// grid: (80 d-chunks of 64, 16 b-groups of 16), block 256, no LDS, no barrier.
__global__ __launch_bounds__(256) void k3_ssm(const float* __restrict__ x,
                                              const float* __restrict__ h0,
                                              const float* __restrict__ dt,
                                              const float* __restrict__ tmp,
                                              const float* __restrict__ Alog,
                                              float* __restrict__ out) {
    const int tid = threadIdx.x;
    const int q = tid >> 2;                  // 0..63 -> d within chunk
    const int l = tid & 3;                   // n-chunk (4 n's)
    const int d = blockIdx.x * 64 + q;
    const int b0 = blockIdx.y * 16;

    // negA for this thread's (d, 4 n's) — contiguous wave-load, 4 exps, once.
    const float4 av = *(const float4*)&Alog[(size_t)d * NN + l * 4];
    const float na[4] = {-__expf(av.x), -__expf(av.y), -__expf(av.z), -__expf(av.w)};

    #pragma unroll 4
    for (int bi = 0; bi < 16; ++bi) {
        const int b = b0 + bi;
        const size_t bd = (size_t)b * DD + d;
        // h0: 16 B/lane, consecutive lanes consecutive addresses -> 1 KB/wave
        const float4 h4 = *(const float4*)&h0[bd * NN + l * 4];
        const float dtv = dt[bd];            // quad-broadcast (16 words/wave)
        const float xv  = x[bd];             // quad-broadcast
        const float4 bm4 = *(const float4*)&tmp[(size_t)b * CT + RR + l * 4];       // Bm
        const float4 cm4 = *(const float4*)&tmp[(size_t)b * CT + RR + 16 + l * 4];  // Cm
        const float dtx = dtv * xv;

        float p0, p1;
        p0 = fmaf(__expf(na[0] * dtv), h4.x, dtx * bm4.x) * cm4.x;
        p1 = fmaf(__expf(na[1] * dtv), h4.y, dtx * bm4.y) * cm4.y;
        p0 = fmaf(fmaf(__expf(na[2] * dtv), h4.z, dtx * bm4.z), cm4.z, p0);
        p1 = fmaf(fmaf(__expf(na[3] * dtv), h4.w, dtx * bm4.w), cm4.w, p1);
        float p = p0 + p1;
        // reduce across the quad (n-sum)
        p += __shfl_xor(p, 1);
        p += __shfl_xor(p, 2);
        if (l == 0) out[bd] = xv + p;        // 16 consecutive floats per wave
    }
}

extern "C" void kernel_launch(void* const* d_in, const int* in_sizes, int n_in,
                              void* d_out, int out_size, void* d_ws, size_t ws_size,
                              hipStream_t stream) {
    const float* x    = (const float*)d_in[0];
    const float* h0   = (const float*)d_in[1];
    const float* Wxdt = (const float*)d_in[2];
    const float* Wdt  = (const float*)d_in[3];
    const float* bdt  = (const float*)d_in[4];
    const float* Wbc  = (const float*)d_in[5];
    const float* Alog = (const float*)d_in[6];
    float* out = (float*)d_out;

    // ws layout (floats): partials[64*49152] | tmp[49152] | dt[1310720]
    float* part  = (float*)d_ws;
    float* tmp   = part + (size_t)NSPLIT * TMP_ELEMS;
    float* dtbuf = tmp + TMP_ELEMS;

    k1_gemm<<<dim3(3, 4, NSPLIT), 256, 0, stream>>>(x, Wxdt, Wbc, part);
    k_red<<<dim3(TMP_ELEMS / 256), 256, 0, stream>>>(part, tmp);
    k2_dt<<<dim3(DD / 64, BB / 32), 256, 0, stream>>>(tmp, Wdt, bdt, dtbuf);
    k3_ssm<<<dim3(DD / 64, BB / 16), 256, 0, stream>>>(x, h0, dtbuf, tmp, Alog, out);
}